// Round 6
// baseline (131.495 us; speedup 1.0000x reference)
//
#include <hip/hip_runtime.h>

#define Wd 64
#define Hd 64
#define HWp 4096
#define CIN_ 128
#define COUT_ 128

typedef _Float16 f16;
typedef _Float16 h2    __attribute__((ext_vector_type(2)));
typedef _Float16 f16x8 __attribute__((ext_vector_type(8)));
typedef float f32x4    __attribute__((ext_vector_type(4)));

__device__ inline ushort f2h(float f) {
    f16 h = (f16)f;
    return __builtin_bit_cast(ushort, h);
}
__device__ inline h2 gb(const int4& g, int d) {
    return __builtin_bit_cast(h2, (&g.x)[d]);
}
__device__ inline h2 dup(float f) {
    f16 h = (f16)f;
    h2 r; r[0] = h; r[1] = h;
    return r;
}
struct H8 { h2 r[4]; };

// ---------------------------------------------------------------------------
// K_prep (1344 blocks): unchanged.
// ---------------------------------------------------------------------------
__global__ __launch_bounds__(256) void prep_offsets_kernel(
    const float* __restrict__ x, const float* __restrict__ w,
    const float* __restrict__ w_off, const float* __restrict__ b_off,
    ushort* __restrict__ xt, ushort* __restrict__ w_t2,
    float4* __restrict__ der)
{
    __shared__ char smem[34816];
    int blk = blockIdx.x;
    int t = threadIdx.x;

    if (blk < 256) {
        ushort* tile = (ushort*)smem;                 // [128][136]
        int b = blk >> 5, yx0 = (blk & 31) << 7;
        const float* xb = x + (size_t)b * CIN_ * HWp + yx0;
        int lanelo = t & 31, grp = t >> 5;
        #pragma unroll
        for (int i = 0; i < 4; i++) {
            int cbase = i * 32 + grp * 4;
            float4 v0 = *(const float4*)(xb + (size_t)(cbase + 0) * HWp + lanelo * 4);
            float4 v1 = *(const float4*)(xb + (size_t)(cbase + 1) * HWp + lanelo * 4);
            float4 v2 = *(const float4*)(xb + (size_t)(cbase + 2) * HWp + lanelo * 4);
            float4 v3 = *(const float4*)(xb + (size_t)(cbase + 3) * HWp + lanelo * 4);
            ushort4 u;
            u.x = f2h(v0.x); u.y = f2h(v1.x); u.z = f2h(v2.x); u.w = f2h(v3.x);
            *(ushort4*)&tile[(lanelo * 4 + 0) * 136 + cbase] = u;
            u.x = f2h(v0.y); u.y = f2h(v1.y); u.z = f2h(v2.y); u.w = f2h(v3.y);
            *(ushort4*)&tile[(lanelo * 4 + 1) * 136 + cbase] = u;
            u.x = f2h(v0.z); u.y = f2h(v1.z); u.z = f2h(v2.z); u.w = f2h(v3.z);
            *(ushort4*)&tile[(lanelo * 4 + 2) * 136 + cbase] = u;
            u.x = f2h(v0.w); u.y = f2h(v1.w); u.z = f2h(v2.w); u.w = f2h(v3.w);
            *(ushort4*)&tile[(lanelo * 4 + 3) * 136 + cbase] = u;
        }
        __syncthreads();
        ushort* dst = xt + ((size_t)b * HWp + yx0) * CIN_;
        int c8 = (t & 15) * 8, yxg = t >> 4;
        #pragma unroll
        for (int i = 0; i < 8; i++) {
            int yxl = i * 16 + yxg;
            int4 v = *(int4*)&tile[yxl * 136 + c8];
            *(int4*)(dst + (size_t)yxl * CIN_ + c8) = v;
        }
    } else if (blk < 832) {
        int i = (blk - 256) * 256 + t;               // 147456 total
        int j    = i & 7;
        int lane = (i >> 3) & 63;
        int ii   = (i >> 9) & 3;
        int wm   = (i >> 11) & 1;
        int s    = i >> 12;
        int o = wm * 64 + ii * 16 + (lane & 15);
        int c = (s & 3) * 32 + (lane >> 4) * 8 + j;
        int k = s >> 2;
        w_t2[i] = f2h(w[o * 1152 + c * 9 + k]);
    } else {
        float* wl   = (float*)smem;                   // 4608 f
        float* part = (float*)(smem + 18432);         // 1024 f
        int blk2 = blk - 832;
        int b = blk2 >> 6;
        int h = blk2 & 63;

        for (int i = t; i < 4608; i += 256) {
            int j = i / 1152;
            int r = i - j * 1152;                     // c*9 + tap
            wl[r * 4 + j] = w_off[i];
        }
        __syncthreads();

        int pi = t & 63, cc = t >> 6;
        const float* xb = x + (size_t)(b * CIN_ + cc * 32) * HWp;

        int idx9[9];
        float msk9[9];
        #pragma unroll
        for (int dy = 0; dy < 3; dy++) {
            int hy = h + dy - 1;
            int hyc = min(max(hy, 0), Hd - 1);
            bool vr = (hy >= 0) && (hy < Hd);
            #pragma unroll
            for (int dx = 0; dx < 3; dx++) {
                int wx = pi + dx - 1;
                int wxc = min(max(wx, 0), Wd - 1);
                bool v = vr && (wx >= 0) && (wx < Wd);
                idx9[dy * 3 + dx] = hyc * Wd + wxc;
                msk9[dy * 3 + dx] = v ? 1.0f : 0.0f;
            }
        }

        float o0 = 0.f, o1 = 0.f, o2 = 0.f, o3 = 0.f;
        #pragma unroll 4
        for (int c = 0; c < 32; c++) {
            const float* xp = xb + c * HWp;
            const float* wc = &wl[(cc * 32 + c) * 36];
            float xv[9];
            #pragma unroll
            for (int tp = 0; tp < 9; tp++) xv[tp] = xp[idx9[tp]] * msk9[tp];
            #pragma unroll
            for (int tp = 0; tp < 9; tp++) {
                float4 wj = *(const float4*)&wc[tp * 4];
                o0 += xv[tp] * wj.x; o1 += xv[tp] * wj.y;
                o2 += xv[tp] * wj.z; o3 += xv[tp] * wj.w;
            }
        }
        part[t * 4 + 0] = o0;
        part[t * 4 + 1] = o1;
        part[t * 4 + 2] = o2;
        part[t * 4 + 3] = o3;
        __syncthreads();

        if (t < 64) {
            float s0 = b_off[0], s1 = b_off[1], s2 = b_off[2], s3 = b_off[3];
            #pragma unroll
            for (int q = 0; q < 4; q++) {
                s0 += part[(q * 64 + t) * 4 + 0];
                s1 += part[(q * 64 + t) * 4 + 1];
                s2 += part[(q * 64 + t) * 4 + 2];
                s3 += part[(q * 64 + t) * 4 + 3];
            }
            float4 d;
            d.x = s0;
            d.y = s1;
            d.z = fmaxf(s2, 0.f) + 1.f;
            d.w = fmaxf(s3, 0.f) + 1.f;
            der[(size_t)b * HWp + h * Wd + t] = d;
        }
    }
}

// ---------------------------------------------------------------------------
// K3 REWRITE: register-direct B-fragments (no S_lds).
// mfma_16x16x32_f16 B-frag layout: lane l needs channels lq*8..+7 at ONE
// position lm -> exactly one int4 gather per bilinear corner. Each lane
// gathers its own 4 corners and combines in registers -> B-frag directly.
// Wave owns full M=128 (8 MFMAs per 32c chunk, acc[8]) x 16 p-cols.
// Block = 4 waves = 64 p. Barrier now gates ONLY the A (weights) staging;
// a slow gather stalls only its own wave (1-chunk reg prefetch, counted
// vmcnt 8/8/4, never 0 mid-loop). LDS 50 KB, no S writes at all.
// ---------------------------------------------------------------------------
__global__ __launch_bounds__(256, 3) void deform_gemm_mfma(
    const ushort* __restrict__ xt, const ushort* __restrict__ w_t2,
    const float* __restrict__ bias, const float4* __restrict__ der,
    float* __restrict__ out)
{
    __shared__ ushort A_lds[2][2][4096];      // 32 KiB: [buf][chunk][8 otile * 512]
    __shared__ int4 MI[9][64];                // 9 KiB corner byte-offsets (pos<<8)
    __shared__ int4 MW[9][64];                // 9 KiB dup-f16 weights (H8)

    int t = threadIdx.x;
    int b = blockIdx.x & 7;                   // XCD-local batch
    int rp = blockIdx.x >> 3;                 // 0..63
    int p0 = rp << 6;
    const char* xtb = (const char*)(xt + (size_t)b * HWp * CIN_);

    int wv = t >> 6, lane = t & 63;           // 4 waves
    int lm = lane & 15, lq = lane >> 4;
    int myp = wv * 16 + lm;                   // this lane's p within tile
    int lqb = lq * 16;                        // byte offset of its 8-chan slice

    f32x4 acc[8] = {};

    // ---- one-time meta: 4 threads per p split the 9 taps -------------------
    {
        int p = t >> 2;
        int pg = p0 + p;
        float fh = (float)(pg >> 6), fp = (float)(pg & 63);
        float4 dv = der[(size_t)b * HWp + pg];   // {sy, sx, sc1, sc2}
        for (int k = (t & 3); k < 9; k += 4) {
            int ky = (k * 11) >> 5;              // k/3 for 0..8
            int kx = k - ky * 3;
            float by = (float)(ky - 1), bx = (float)(kx - 1);
            bool corner = (ky != 1) && (kx != 1);
            bool edge = (ky != 1) ^ (kx != 1);
            float sk = corner ? dv.z : (edge ? dv.w : 0.0f);
            float py = fh + by * sk + dv.x;
            float px = fp + bx * sk + dv.y;
            float y0f = floorf(py), x0f = floorf(px);
            float wy = py - y0f, wx = px - x0f;
            int y0 = (int)y0f, x0 = (int)x0f;
            int y1 = y0 + 1, x1 = x0 + 1;
            float vy0 = (y0 >= 0 && y0 < Hd) ? 1.f : 0.f;
            float vy1 = (y1 >= 0 && y1 < Hd) ? 1.f : 0.f;
            float vx0 = (x0 >= 0 && x0 < Wd) ? 1.f : 0.f;
            float vx1 = (x1 >= 0 && x1 < Wd) ? 1.f : 0.f;
            int cy0 = min(max(y0, 0), Hd - 1), cy1 = min(max(y1, 0), Hd - 1);
            int cx0 = min(max(x0, 0), Wd - 1), cx1 = min(max(x1, 0), Wd - 1);
            int4 ii;
            ii.x = (cy0 * Wd + cx0) << 8;        // * CIN_ * 2 bytes
            ii.y = (cy0 * Wd + cx1) << 8;
            ii.z = (cy1 * Wd + cx0) << 8;
            ii.w = (cy1 * Wd + cx1) << 8;
            MI[k][p] = ii;
            H8 hw;
            hw.r[0] = dup((1.f - wy) * (1.f - wx) * vy0 * vx0);
            hw.r[1] = dup((1.f - wy) * wx * vy0 * vx1);
            hw.r[2] = dup(wy * (1.f - wx) * vy1 * vx0);
            hw.r[3] = dup(wy * wx * vy1 * vx1);
            MW[k][p] = __builtin_bit_cast(int4, hw);
        }
    }
    __syncthreads();

    int vo0, vo1, vo2, vo3;          // per-lane corner byte offsets (cur tap)

    // async A staging: stage st covers w_t2 ushorts [st*8192, st*8192+8192).
    auto stageA = [&](int buf, int st) {
        const ushort* src = w_t2 + (size_t)st * 8192;
        #pragma unroll
        for (int cc = 0; cc < 2; cc++) {
            #pragma unroll
            for (int hrow = 0; hrow < 2; hrow++) {
                const ushort* g = src + cc * 4096 + (wv * 2 + hrow) * 512 + lane * 8;
                ushort* l = &A_lds[buf][cc][(wv * 2 + hrow) * 512];
                __builtin_amdgcn_global_load_lds(
                    (const __attribute__((address_space(1))) unsigned int*)g,
                    (__attribute__((address_space(3))) unsigned int*)l, 16, 0, 0);
            }
        }
    };

    // per-lane 4-corner gather for one 32c chunk (qm = chunk & 3 within tap)
    auto issueG = [&](int4 (&G)[4], int qm) {
        int off = qm * 64;
        G[0] = *(const int4*)(xtb + (vo0 + off));
        G[1] = *(const int4*)(xtb + (vo1 + off));
        G[2] = *(const int4*)(xtb + (vo2 + off));
        G[3] = *(const int4*)(xtb + (vo3 + off));
    };

    // combine 4 corners -> B-frag, then 8 MFMAs over the M=128 o-tiles
    auto mfmaChunk = [&](int cur, int cc, const int4 (&G)[4], const H8& cw) {
        H8 tmp;
        #pragma unroll
        for (int d = 0; d < 4; d++) {
            h2 r = gb(G[0], d) * cw.r[0];
            r = gb(G[1], d) * cw.r[1] + r;
            r = gb(G[2], d) * cw.r[2] + r;
            r = gb(G[3], d) * cw.r[3] + r;
            tmp.r[d] = r;
        }
        f16x8 bf = __builtin_bit_cast(f16x8, tmp);
        __builtin_amdgcn_s_setprio(1);
        #pragma unroll
        for (int i = 0; i < 8; i++) {
            f16x8 af = *(const f16x8*)&A_lds[cur][cc][i * 512 + lane * 8];
            acc[i] = __builtin_amdgcn_mfma_f32_16x16x32_f16(af, bf, acc[i], 0, 0, 0);
        }
        __builtin_amdgcn_s_setprio(0);
    };

    int4 GA[4], GB[4];               // gather ping-pong (even / odd chunk)
    H8 cwA, cwB;
    int4 idxN;

    // prologue: tap0 meta -> regs; A stage0; gather chunk0.
    {
        int4 mi0 = MI[0][myp];
        vo0 = mi0.x + lqb; vo1 = mi0.y + lqb; vo2 = mi0.z + lqb; vo3 = mi0.w + lqb;
        cwA = __builtin_bit_cast(H8, MW[0][myp]);
        idxN = MI[1][myp];
    }
    stageA(0, 0);
    __builtin_amdgcn_sched_barrier(0);
    issueG(GA, 0);
    asm volatile("s_waitcnt vmcnt(4)" ::: "memory");   // A0 done; GA in flight
    __builtin_amdgcn_s_barrier();
    __builtin_amdgcn_sched_barrier(0);

// Stage ST (chunks 2ST, 2ST+1): combine GA then GB; issue GB(2ST+1),
// GA(2ST+2); stage A(ST+1). Counted vmcnt: 8 / 8 / 4 (A drained at barrier,
// next gathers ride across). DORD on odd ST: tap advance via reg-prefetched
// idxN; refill idxN/CWN from LDS tables (clamped tails never consumed).
#define BODY(ST, CWC, CWN, DORD)                                             \
    {                                                                        \
        int cur_ = (ST) & 1, nb_ = cur_ ^ 1;                                 \
        issueG(GB, (2 * (ST) + 1) & 3);                                      \
        stageA(nb_, (ST) + 1);                                               \
        __builtin_amdgcn_sched_barrier(0);                                   \
        asm volatile("s_waitcnt vmcnt(8)" ::: "memory");                     \
        __builtin_amdgcn_sched_barrier(0);                                   \
        mfmaChunk(cur_, 0, GA, CWC);                                         \
        if (DORD) {                                                          \
            vo0 = idxN.x + lqb; vo1 = idxN.y + lqb;                          \
            vo2 = idxN.z + lqb; vo3 = idxN.w + lqb;                          \
        }                                                                    \
        issueG(GA, (2 * (ST) + 2) & 3);                                      \
        if (DORD) {                                                          \
            idxN = MI[min(((ST) >> 1) + 2, 8)][myp];                         \
            CWN  = __builtin_bit_cast(H8, MW[min(((ST) >> 1) + 1, 8)][myp]); \
        }                                                                    \
        __builtin_amdgcn_sched_barrier(0);                                   \
        asm volatile("s_waitcnt vmcnt(8)" ::: "memory");                     \
        __builtin_amdgcn_sched_barrier(0);                                   \
        mfmaChunk(cur_, 1, GB, CWC);                                         \
        asm volatile("s_waitcnt vmcnt(4)" ::: "memory");                     \
        __builtin_amdgcn_s_barrier();                                        \
        __builtin_amdgcn_sched_barrier(0);                                   \
    }

    for (int su = 0; su < 4; su++) {
        int st = su << 2;
        BODY(st,     cwA, cwB, 0);
        BODY(st + 1, cwA, cwB, 1);
        BODY(st + 2, cwB, cwA, 0);
        BODY(st + 3, cwB, cwA, 1);
    }
    BODY(16, cwA, cwB, 0);
#undef BODY

    // stage 17 tail (chunks 34, 35): no further staging/issues.
    {
        issueG(GB, 3);
        __builtin_amdgcn_sched_barrier(0);
        asm volatile("s_waitcnt vmcnt(4)" ::: "memory");
        __builtin_amdgcn_sched_barrier(0);
        mfmaChunk(1, 0, GA, cwA);
        asm volatile("s_waitcnt vmcnt(0)" ::: "memory");
        __builtin_amdgcn_sched_barrier(0);
        mfmaChunk(1, 1, GB, cwA);
    }

    // epilogue: C layout col(p)=lane&15, row(o)=(lane>>4)*4+reg.
    // af index I -> o-base = (I>>2)*64 + (I&3)*16 (w_t2 fragment order).
    int pgo = p0 + wv * 16 + lm;
    #pragma unroll
    for (int I = 0; I < 8; I++) {
        int ob = (I >> 2) * 64 + (I & 3) * 16 + lq * 4;
        #pragma unroll
        for (int r = 0; r < 4; r++) {
            int o = ob + r;
            float bv = bias[o];
            __builtin_nontemporal_store(acc[I][r] + bv,
                out + (size_t)(b * COUT_ + o) * HWp + pgo);
        }
    }
}

extern "C" void kernel_launch(void* const* d_in, const int* in_sizes, int n_in,
                              void* d_out, int out_size, void* d_ws, size_t ws_size,
                              hipStream_t stream) {
    const float* x     = (const float*)d_in[0];
    const float* w_off = (const float*)d_in[1];
    const float* b_off = (const float*)d_in[2];
    const float* w     = (const float*)d_in[3];
    const float* bias  = (const float*)d_in[4];
    float* out = (float*)d_out;

    char* ws = (char*)d_ws;
    ushort* xt   = (ushort*)ws;                          // 8 MiB (f16 NHWC)
    ushort* w_t2 = (ushort*)(ws + 8388608);              // 294912 B (f16 frag order)
    float4* der  = (float4*)(ws + 8683520);              // 512 KiB {sy,sx,sc1,sc2}/pos

    prep_offsets_kernel<<<1344, 256, 0, stream>>>(x, w, w_off, b_off,
                                                  xt, w_t2, der);
    deform_gemm_mfma<<<512, 256, 0, stream>>>(xt, w_t2, bias, der, out);
}

// Round 7
// 129.158 us; speedup vs baseline: 1.0181x; 1.0181x over previous
//
#include <hip/hip_runtime.h>

#define Wd 64
#define Hd 64
#define HWp 4096
#define CIN_ 128
#define COUT_ 128

typedef _Float16 f16;
typedef _Float16 h2    __attribute__((ext_vector_type(2)));
typedef _Float16 f16x8 __attribute__((ext_vector_type(8)));
typedef float f32x4    __attribute__((ext_vector_type(4)));

__device__ inline ushort f2h(float f) {
    f16 h = (f16)f;
    return __builtin_bit_cast(ushort, h);
}
__device__ inline h2 gb(const int4& g, int d) {
    return __builtin_bit_cast(h2, (&g.x)[d]);
}
__device__ inline h2 dup(float f) {
    f16 h = (f16)f;
    h2 r; r[0] = h; r[1] = h;
    return r;
}
struct H8 { h2 r[4]; };

// ---------------------------------------------------------------------------
// K_prep (1344 blocks): unchanged.
// ---------------------------------------------------------------------------
__global__ __launch_bounds__(256) void prep_offsets_kernel(
    const float* __restrict__ x, const float* __restrict__ w,
    const float* __restrict__ w_off, const float* __restrict__ b_off,
    ushort* __restrict__ xt, ushort* __restrict__ w_t2,
    float4* __restrict__ der)
{
    __shared__ char smem[34816];
    int blk = blockIdx.x;
    int t = threadIdx.x;

    if (blk < 256) {
        ushort* tile = (ushort*)smem;                 // [128][136]
        int b = blk >> 5, yx0 = (blk & 31) << 7;
        const float* xb = x + (size_t)b * CIN_ * HWp + yx0;
        int lanelo = t & 31, grp = t >> 5;
        #pragma unroll
        for (int i = 0; i < 4; i++) {
            int cbase = i * 32 + grp * 4;
            float4 v0 = *(const float4*)(xb + (size_t)(cbase + 0) * HWp + lanelo * 4);
            float4 v1 = *(const float4*)(xb + (size_t)(cbase + 1) * HWp + lanelo * 4);
            float4 v2 = *(const float4*)(xb + (size_t)(cbase + 2) * HWp + lanelo * 4);
            float4 v3 = *(const float4*)(xb + (size_t)(cbase + 3) * HWp + lanelo * 4);
            ushort4 u;
            u.x = f2h(v0.x); u.y = f2h(v1.x); u.z = f2h(v2.x); u.w = f2h(v3.x);
            *(ushort4*)&tile[(lanelo * 4 + 0) * 136 + cbase] = u;
            u.x = f2h(v0.y); u.y = f2h(v1.y); u.z = f2h(v2.y); u.w = f2h(v3.y);
            *(ushort4*)&tile[(lanelo * 4 + 1) * 136 + cbase] = u;
            u.x = f2h(v0.z); u.y = f2h(v1.z); u.z = f2h(v2.z); u.w = f2h(v3.z);
            *(ushort4*)&tile[(lanelo * 4 + 2) * 136 + cbase] = u;
            u.x = f2h(v0.w); u.y = f2h(v1.w); u.z = f2h(v2.w); u.w = f2h(v3.w);
            *(ushort4*)&tile[(lanelo * 4 + 3) * 136 + cbase] = u;
        }
        __syncthreads();
        ushort* dst = xt + ((size_t)b * HWp + yx0) * CIN_;
        int c8 = (t & 15) * 8, yxg = t >> 4;
        #pragma unroll
        for (int i = 0; i < 8; i++) {
            int yxl = i * 16 + yxg;
            int4 v = *(int4*)&tile[yxl * 136 + c8];
            *(int4*)(dst + (size_t)yxl * CIN_ + c8) = v;
        }
    } else if (blk < 832) {
        int i = (blk - 256) * 256 + t;               // 147456 total
        int j    = i & 7;
        int lane = (i >> 3) & 63;
        int ii   = (i >> 9) & 3;
        int wm   = (i >> 11) & 1;
        int s    = i >> 12;
        int o = wm * 64 + ii * 16 + (lane & 15);
        int c = (s & 3) * 32 + (lane >> 4) * 8 + j;
        int k = s >> 2;
        w_t2[i] = f2h(w[o * 1152 + c * 9 + k]);
    } else {
        float* wl   = (float*)smem;                   // 4608 f
        float* part = (float*)(smem + 18432);         // 1024 f
        int blk2 = blk - 832;
        int b = blk2 >> 6;
        int h = blk2 & 63;

        for (int i = t; i < 4608; i += 256) {
            int j = i / 1152;
            int r = i - j * 1152;                     // c*9 + tap
            wl[r * 4 + j] = w_off[i];
        }
        __syncthreads();

        int pi = t & 63, cc = t >> 6;
        const float* xb = x + (size_t)(b * CIN_ + cc * 32) * HWp;

        int idx9[9];
        float msk9[9];
        #pragma unroll
        for (int dy = 0; dy < 3; dy++) {
            int hy = h + dy - 1;
            int hyc = min(max(hy, 0), Hd - 1);
            bool vr = (hy >= 0) && (hy < Hd);
            #pragma unroll
            for (int dx = 0; dx < 3; dx++) {
                int wx = pi + dx - 1;
                int wxc = min(max(wx, 0), Wd - 1);
                bool v = vr && (wx >= 0) && (wx < Wd);
                idx9[dy * 3 + dx] = hyc * Wd + wxc;
                msk9[dy * 3 + dx] = v ? 1.0f : 0.0f;
            }
        }

        float o0 = 0.f, o1 = 0.f, o2 = 0.f, o3 = 0.f;
        #pragma unroll 4
        for (int c = 0; c < 32; c++) {
            const float* xp = xb + c * HWp;
            const float* wc = &wl[(cc * 32 + c) * 36];
            float xv[9];
            #pragma unroll
            for (int tp = 0; tp < 9; tp++) xv[tp] = xp[idx9[tp]] * msk9[tp];
            #pragma unroll
            for (int tp = 0; tp < 9; tp++) {
                float4 wj = *(const float4*)&wc[tp * 4];
                o0 += xv[tp] * wj.x; o1 += xv[tp] * wj.y;
                o2 += xv[tp] * wj.z; o3 += xv[tp] * wj.w;
            }
        }
        part[t * 4 + 0] = o0;
        part[t * 4 + 1] = o1;
        part[t * 4 + 2] = o2;
        part[t * 4 + 3] = o3;
        __syncthreads();

        if (t < 64) {
            float s0 = b_off[0], s1 = b_off[1], s2 = b_off[2], s3 = b_off[3];
            #pragma unroll
            for (int q = 0; q < 4; q++) {
                s0 += part[(q * 64 + t) * 4 + 0];
                s1 += part[(q * 64 + t) * 4 + 1];
                s2 += part[(q * 64 + t) * 4 + 2];
                s3 += part[(q * 64 + t) * 4 + 3];
            }
            float4 d;
            d.x = s0;
            d.y = s1;
            d.z = fmaxf(s2, 0.f) + 1.f;
            d.w = fmaxf(s3, 0.f) + 1.f;
            der[(size_t)b * HWp + h * Wd + t] = d;
        }
    }
}

// ---------------------------------------------------------------------------
// K3: register-direct B-fragments (no S_lds) + 4-chunk gather ring.
// Round-6 regression diagnosis: per-chunk issue->wait->mfma serialization
// (prefetch depth ~0.5 chunk) exposed gather latency per chunk. Repair:
// ring of 4 G-buffers; stage ST consumes chunks 2ST/2ST+1 (issued at ST-1),
// issues 2ST+2/2ST+3 -> one full stage of slack, gathers ride across the
// barrier (manual vmcnt(8) drains only A-staging). Register G-loads get
// exact compiler-counted vmcnt waits before each combine. sched_barrier
// pins: stageA first (so end-of-stage count-8 provably drains A), all
// issues before the MFMA cluster. 2 independent blocks/CU kept.
// ---------------------------------------------------------------------------
__global__ __launch_bounds__(256, 2) void deform_gemm_mfma(
    const ushort* __restrict__ xt, const ushort* __restrict__ w_t2,
    const float* __restrict__ bias, const float4* __restrict__ der,
    float* __restrict__ out)
{
    __shared__ ushort A_lds[2][2][4096];      // 32 KiB: [buf][chunk][8 otile * 512]
    __shared__ int4 MI[9][64];                // 9 KiB corner byte-offsets (pos<<8)
    __shared__ int4 MW[9][64];                // 9 KiB dup-f16 weights (H8)

    int t = threadIdx.x;
    int b = blockIdx.x & 7;                   // XCD-local batch
    int rp = blockIdx.x >> 3;                 // 0..63
    int p0 = rp << 6;
    const char* xtb = (const char*)(xt + (size_t)b * HWp * CIN_);

    int wv = t >> 6, lane = t & 63;           // 4 waves
    int lm = lane & 15, lq = lane >> 4;
    int myp = wv * 16 + lm;                   // this lane's p within tile
    int lqb = lq * 16;                        // byte offset of its 8-chan slice

    f32x4 acc[8] = {};

    // ---- one-time meta: 4 threads per p split the 9 taps -------------------
    {
        int p = t >> 2;
        int pg = p0 + p;
        float fh = (float)(pg >> 6), fp = (float)(pg & 63);
        float4 dv = der[(size_t)b * HWp + pg];   // {sy, sx, sc1, sc2}
        for (int k = (t & 3); k < 9; k += 4) {
            int ky = (k * 11) >> 5;              // k/3 for 0..8
            int kx = k - ky * 3;
            float by = (float)(ky - 1), bx = (float)(kx - 1);
            bool corner = (ky != 1) && (kx != 1);
            bool edge = (ky != 1) ^ (kx != 1);
            float sk = corner ? dv.z : (edge ? dv.w : 0.0f);
            float py = fh + by * sk + dv.x;
            float px = fp + bx * sk + dv.y;
            float y0f = floorf(py), x0f = floorf(px);
            float wy = py - y0f, wx = px - x0f;
            int y0 = (int)y0f, x0 = (int)x0f;
            int y1 = y0 + 1, x1 = x0 + 1;
            float vy0 = (y0 >= 0 && y0 < Hd) ? 1.f : 0.f;
            float vy1 = (y1 >= 0 && y1 < Hd) ? 1.f : 0.f;
            float vx0 = (x0 >= 0 && x0 < Wd) ? 1.f : 0.f;
            float vx1 = (x1 >= 0 && x1 < Wd) ? 1.f : 0.f;
            int cy0 = min(max(y0, 0), Hd - 1), cy1 = min(max(y1, 0), Hd - 1);
            int cx0 = min(max(x0, 0), Wd - 1), cx1 = min(max(x1, 0), Wd - 1);
            int4 ii;
            ii.x = (cy0 * Wd + cx0) << 8;        // * CIN_ * 2 bytes
            ii.y = (cy0 * Wd + cx1) << 8;
            ii.z = (cy1 * Wd + cx0) << 8;
            ii.w = (cy1 * Wd + cx1) << 8;
            MI[k][p] = ii;
            H8 hw;
            hw.r[0] = dup((1.f - wy) * (1.f - wx) * vy0 * vx0);
            hw.r[1] = dup((1.f - wy) * wx * vy0 * vx1);
            hw.r[2] = dup(wy * (1.f - wx) * vy1 * vx0);
            hw.r[3] = dup(wy * wx * vy1 * vx1);
            MW[k][p] = __builtin_bit_cast(int4, hw);
        }
    }
    __syncthreads();

    int vo0, vo1, vo2, vo3;          // per-lane corner byte offsets (cur tap)

    // async A staging: stage st covers w_t2 ushorts [st*8192, st*8192+8192).
    auto stageA = [&](int buf, int st) {
        const ushort* src = w_t2 + (size_t)st * 8192;
        #pragma unroll
        for (int cc = 0; cc < 2; cc++) {
            #pragma unroll
            for (int hrow = 0; hrow < 2; hrow++) {
                const ushort* g = src + cc * 4096 + (wv * 2 + hrow) * 512 + lane * 8;
                ushort* l = &A_lds[buf][cc][(wv * 2 + hrow) * 512];
                __builtin_amdgcn_global_load_lds(
                    (const __attribute__((address_space(1))) unsigned int*)g,
                    (__attribute__((address_space(3))) unsigned int*)l, 16, 0, 0);
            }
        }
    };

    // per-lane 4-corner gather for one 32c chunk (qm = chunk & 3 within tap)
    auto issueG = [&](int4 (&G)[4], int qm) {
        int off = qm * 64;
        G[0] = *(const int4*)(xtb + (vo0 + off));
        G[1] = *(const int4*)(xtb + (vo1 + off));
        G[2] = *(const int4*)(xtb + (vo2 + off));
        G[3] = *(const int4*)(xtb + (vo3 + off));
    };

    // combine 4 corners -> B-frag, then 8 MFMAs over the M=128 o-tiles
    auto mfmaChunk = [&](int cur, int cc, const int4 (&G)[4], const H8& cw) {
        H8 tmp;
        #pragma unroll
        for (int d = 0; d < 4; d++) {
            h2 r = gb(G[0], d) * cw.r[0];
            r = gb(G[1], d) * cw.r[1] + r;
            r = gb(G[2], d) * cw.r[2] + r;
            r = gb(G[3], d) * cw.r[3] + r;
            tmp.r[d] = r;
        }
        f16x8 bf = __builtin_bit_cast(f16x8, tmp);
        __builtin_amdgcn_s_setprio(1);
        #pragma unroll
        for (int i = 0; i < 8; i++) {
            f16x8 af = *(const f16x8*)&A_lds[cur][cc][i * 512 + lane * 8];
            acc[i] = __builtin_amdgcn_mfma_f32_16x16x32_f16(af, bf, acc[i], 0, 0, 0);
        }
        __builtin_amdgcn_s_setprio(0);
    };

    int4 G0[4], G1[4], G2[4], G3[4]; // 4-chunk ring: chunk n -> G[n%4]
    H8 cwA, cwB;
    int4 idxN;

    // prologue: tap0 meta -> regs; A stage0 (pinned first); gather chunks 0,1.
    {
        int4 mi0 = MI[0][myp];
        vo0 = mi0.x + lqb; vo1 = mi0.y + lqb; vo2 = mi0.z + lqb; vo3 = mi0.w + lqb;
        cwA = __builtin_bit_cast(H8, MW[0][myp]);
        idxN = MI[1][myp];
    }
    stageA(0, 0);
    __builtin_amdgcn_sched_barrier(0);
    issueG(G0, 0);
    issueG(G1, 1);
    __builtin_amdgcn_sched_barrier(0);
    asm volatile("s_waitcnt vmcnt(8)" ::: "memory");   // A0 done; G0,G1 ride
    __builtin_amdgcn_s_barrier();
    __builtin_amdgcn_sched_barrier(0);

// Stage ST: consume GC0(chunk 2ST), GC1(2ST+1) [issued at ST-1]; stage
// A(ST+1) [pinned first]; issue GI0(2ST+2), GI1(2ST+3). DORD on odd ST:
// advance vo to tap (ST+1)/2 from reg-prefetched idxN BEFORE issues, then
// refill idxN/CWN from LDS tables (clamped tails never consumed). Compiler
// inserts exact counted vmcnt before each combine; manual vmcnt(8) at the
// raw barrier drains A only (8 gather loads stay in flight across it).
#define SBODY(ST, GC0, GC1, GI0, GI1, CWC, CWN, DORD)                        \
    {                                                                        \
        int cur_ = (ST) & 1, nb_ = cur_ ^ 1;                                 \
        stageA(nb_, (ST) + 1);                                               \
        __builtin_amdgcn_sched_barrier(0);                                   \
        if (DORD) {                                                          \
            vo0 = idxN.x + lqb; vo1 = idxN.y + lqb;                          \
            vo2 = idxN.z + lqb; vo3 = idxN.w + lqb;                          \
        }                                                                    \
        issueG(GI0, (2 * (ST) + 2) & 3);                                     \
        issueG(GI1, (2 * (ST) + 3) & 3);                                     \
        if (DORD) {                                                          \
            idxN = MI[min(((ST) >> 1) + 2, 8)][myp];                         \
            CWN  = __builtin_bit_cast(H8, MW[min(((ST) >> 1) + 1, 8)][myp]); \
        }                                                                    \
        __builtin_amdgcn_sched_barrier(0);                                   \
        mfmaChunk(cur_, 0, GC0, CWC);                                        \
        mfmaChunk(cur_, 1, GC1, CWC);                                        \
        asm volatile("s_waitcnt vmcnt(8)" ::: "memory");                     \
        __builtin_amdgcn_s_barrier();                                        \
        __builtin_amdgcn_sched_barrier(0);                                   \
    }

    for (int su = 0; su < 4; su++) {
        int st = su << 2;
        SBODY(st,     G0, G1, G2, G3, cwA, cwB, 0);
        SBODY(st + 1, G2, G3, G0, G1, cwA, cwB, 1);
        SBODY(st + 2, G0, G1, G2, G3, cwB, cwA, 0);
        SBODY(st + 3, G2, G3, G0, G1, cwB, cwA, 1);
    }
    SBODY(16, G0, G1, G2, G3, cwA, cwB, 0);
#undef SBODY

    // stage 17 tail: consume G2 (chunk 34), G3 (chunk 35); tap 8 weights=cwA.
    {
        __builtin_amdgcn_sched_barrier(0);
        mfmaChunk(1, 0, G2, cwA);
        mfmaChunk(1, 1, G3, cwA);
    }

    // epilogue: C layout col(p)=lane&15, row(o)=(lane>>4)*4+reg.
    // af index I -> o-base = (I>>2)*64 + (I&3)*16 (w_t2 fragment order).
    int pgo = p0 + wv * 16 + lm;
    #pragma unroll
    for (int I = 0; I < 8; I++) {
        int ob = (I >> 2) * 64 + (I & 3) * 16 + lq * 4;
        #pragma unroll
        for (int r = 0; r < 4; r++) {
            int o = ob + r;
            float bv = bias[o];
            __builtin_nontemporal_store(acc[I][r] + bv,
                out + (size_t)(b * COUT_ + o) * HWp + pgo);
        }
    }
}

extern "C" void kernel_launch(void* const* d_in, const int* in_sizes, int n_in,
                              void* d_out, int out_size, void* d_ws, size_t ws_size,
                              hipStream_t stream) {
    const float* x     = (const float*)d_in[0];
    const float* w_off = (const float*)d_in[1];
    const float* b_off = (const float*)d_in[2];
    const float* w     = (const float*)d_in[3];
    const float* bias  = (const float*)d_in[4];
    float* out = (float*)d_out;

    char* ws = (char*)d_ws;
    ushort* xt   = (ushort*)ws;                          // 8 MiB (f16 NHWC)
    ushort* w_t2 = (ushort*)(ws + 8388608);              // 294912 B (f16 frag order)
    float4* der  = (float4*)(ws + 8683520);              // 512 KiB {sy,sx,sc1,sc2}/pos

    prep_offsets_kernel<<<1344, 256, 0, stream>>>(x, w, w_off, b_off,
                                                  xt, w_t2, der);
    deform_gemm_mfma<<<512, 256, 0, stream>>>(xt, w_t2, bias, der, out);
}